// Round 7
// baseline (275.280 us; speedup 1.0000x reference)
//
#include <hip/hip_runtime.h>
#include <math.h>

#define Bn   1024
#define Fdim 256
#define Nn   65536
#define Cn   1000
#define INV_TEMP 20.0f
#define MOM  0.2f

// ---------------- workspace layout (all 4-byte types, no padding) ----------
// meanP, counts, sumExp are contiguous at the tail -> zeroed by ONE memset.
struct WS {
  float x[Bn * Fdim];       // normalized inputs                    (1 MB)
  float tExp[Bn];
  int   idx[Bn];
  int   targets[Bn];
  int   offsets[Cn];
  int   cursor[Cn];
  int   list[Nn];
  // ---- zero region start (offset 1331008 B, 16B-aligned) ----
  float meanP[Fdim * Cn];   // class SUMS, packed [f/4][Cn][4]      (1 MB)
  int   counts[Cn];
  float sumExp[Bn];
  // ---- zero region end ----
};

// K1: x = inputs/||inputs|| (one wave per row, float4) + idx/target remap
//     + fused label histogram (this grid has exactly Nn threads).
__global__ __launch_bounds__(64) void k1_norm(const float* __restrict__ inputs,
                                              const int* __restrict__ indexes,
                                              const int* __restrict__ labels,
                                              float* __restrict__ x,
                                              int* __restrict__ idx, int* __restrict__ targets,
                                              int* __restrict__ counts) {
  int b = blockIdx.x, t = threadIdx.x;
  atomicAdd(&counts[labels[b * 64 + t]], 1);   // histogram: one thread per bank row
  float4 v = *(const float4*)&inputs[b * Fdim + t * 4];
  float s = v.x * v.x + v.y * v.y + v.z * v.z + v.w * v.w;
#pragma unroll
  for (int o = 32; o > 0; o >>= 1) s += __shfl_xor(s, o, 64);
  float inv = 1.0f / sqrtf(s);
  v.x *= inv; v.y *= inv; v.z *= inv; v.w *= inv;
  *(float4*)&x[b * Fdim + t * 4] = v;
  if (t == 0) {
    int i0 = indexes[b] - 1;
    if (i0 == 5554) i0 = 750;   // is_source special case -> SOURCE_CLASSES-1
    idx[b] = i0;
    targets[b] = labels[i0];
  }
}

// K3: exclusive scan of counts -> offsets, cursor (single block, 1024 threads)
__global__ void k3_scan(const int* __restrict__ counts, int* __restrict__ offsets,
                        int* __restrict__ cursor) {
  __shared__ int s[1024];
  int t = threadIdx.x;
  int v = (t < Cn) ? counts[t] : 0;
  s[t] = v;
  __syncthreads();
  for (int o = 1; o < 1024; o <<= 1) {
    int a = (t >= o) ? s[t - o] : 0;
    __syncthreads();
    s[t] += a;
    __syncthreads();
  }
  if (t < Cn) {
    int off = s[t] - v;
    offsets[t] = off;
    cursor[t] = off;
  }
}

// K4: fill per-class member lists (int4 loads) -> list is class-sorted
__global__ __launch_bounds__(256) void k4_fill(const int* __restrict__ labels,
                                               int* __restrict__ cursor,
                                               int* __restrict__ list) {
  int t = blockIdx.x * blockDim.x + threadIdx.x;
  int4 l = *(const int4*)&labels[t * 4];
  int n = t * 4;
  list[atomicAdd(&cursor[l.x], 1)] = n;
  list[atomicAdd(&cursor[l.y], 1)] = n + 1;
  list[atomicAdd(&cursor[l.z], 1)] = n + 2;
  list[atomicAdd(&cursor[l.w], 1)] = n + 3;
}

// K5: fused bank-copy + class-sum over the class-sorted list. Wave g handles
// entries [g*16, g*16+16). All 16 row indices and labels are fetched first
// (2 serial round trips), then rows stream 8-deep. Run-boundary flushes
// (~1.24/wave expected) atomicAdd straight into the PACKED meanP layout:
// lane's 4 f-elements are 16B contiguous at meanP[(lane*Cn + c)*4].
__global__ __launch_bounds__(256) void k5_fused(const float* __restrict__ features,
                                                const int* __restrict__ list,
                                                const int* __restrict__ labels,
                                                float* __restrict__ meanP,
                                                float* __restrict__ out1) {
  int w = blockIdx.x * 4 + (threadIdx.x >> 6);   // global wave id, 0..4095
  int lane = threadIdx.x & 63;
  int e0 = w * 16;
  int r[16], cc[16];
#pragma unroll
  for (int j = 0; j < 16; j++) r[j] = list[e0 + j];      // wave-uniform
#pragma unroll
  for (int j = 0; j < 16; j++) cc[j] = labels[r[j]];     // wave-uniform
  float4 acc = {0.f, 0.f, 0.f, 0.f};
  int cur = cc[0];
#pragma unroll
  for (int bh = 0; bh < 2; bh++) {
    float4 v[8];
#pragma unroll
    for (int j = 0; j < 8; j++)
      v[j] = *(const float4*)&features[(size_t)r[bh * 8 + j] * Fdim + lane * 4];
#pragma unroll
    for (int j = 0; j < 8; j++) {
      int e = bh * 8 + j;
      float* o = &out1[(size_t)r[e] * Fdim + lane * 4];  // +1 misaligned -> dword stores
      o[0] = v[j].x; o[1] = v[j].y; o[2] = v[j].z; o[3] = v[j].w;
      if (cc[e] != cur) {                                // wave-uniform branch
        float* p = &meanP[((size_t)lane * Cn + cur) * 4];
        atomicAdd(p + 0, acc.x); atomicAdd(p + 1, acc.y);
        atomicAdd(p + 2, acc.z); atomicAdd(p + 3, acc.w);
        acc.x = 0.f; acc.y = 0.f; acc.z = 0.f; acc.w = 0.f;
        cur = cc[e];
      }
      acc.x += v[j].x; acc.y += v[j].y; acc.z += v[j].z; acc.w += v[j].w;
    }
  }
  float* p = &meanP[((size_t)lane * Cn + cur) * 4];
  atomicAdd(p + 0, acc.x); atomicAdd(p + 1, acc.y);
  atomicAdd(p + 2, acc.z); atomicAdd(p + 3, acc.w);
}

// K6: sim = (x @ classSum^T) * (INV_TEMP/cnt) fused with masked-softmax
// partials. BBT=8 halves meanP L2 re-reads vs BBT=4 (128 MB total). Mask and
// mean-scaling come straight from counts[] (no separate pack/mask pass).
#define BBT 8
__global__ __launch_bounds__(256) void k6_matmul(const float* __restrict__ x,
                                                 const float* __restrict__ meanP,
                                                 const int* __restrict__ counts,
                                                 const int* __restrict__ targets,
                                                 float* __restrict__ sumExp,
                                                 float* __restrict__ tExp) {
  int b0 = blockIdx.x * BBT;
  int c  = blockIdx.y * 256 + threadIdx.x;
  int lane = threadIdx.x & 63;
  bool cv = (c < Cn);
  int cc = cv ? c : 0;
  float acc[BBT];
#pragma unroll
  for (int bb = 0; bb < BBT; bb++) acc[bb] = 0.f;
  const float* xb = x + b0 * Fdim;
#pragma unroll 4
  for (int f4 = 0; f4 < Fdim / 4; f4++) {
    float4 mv = *(const float4*)&meanP[(f4 * Cn + cc) * 4];
#pragma unroll
    for (int bb = 0; bb < BBT; bb++) {
      float4 xv = *(const float4*)&xb[bb * Fdim + f4 * 4];   // uniform address (L1-hot)
      acc[bb] = fmaf(xv.x, mv.x, acc[bb]);
      acc[bb] = fmaf(xv.y, mv.y, acc[bb]);
      acc[bb] = fmaf(xv.z, mv.z, acc[bb]);
      acc[bb] = fmaf(xv.w, mv.w, acc[bb]);
    }
  }
  int cnt = counts[cc];
  bool live = cv && (cnt > 0);
  float scale = live ? (INV_TEMP / (float)cnt) : 0.f;
#pragma unroll
  for (int bb = 0; bb < BBT; bb++) {
    float e = live ? __expf(acc[bb] * scale) : 0.f;
    float s = e;
#pragma unroll
    for (int o = 32; o > 0; o >>= 1) s += __shfl_down(s, o, 64);
    if (lane == 0) atomicAdd(&sumExp[b0 + bb], s);
    int tgt = targets[b0 + bb];
    if (cv && tgt == c) tExp[b0 + bb] = e;
  }
}

// K8: sequential momentum scatter update (blocks 0..255) + final loss
// reduction (block 256). One wave per sample b; only the first occurrence of
// each index runs, processing its whole duplicate chain in ascending b order.
__global__ __launch_bounds__(256) void k8_update(const float* __restrict__ features,
                                                 const float* __restrict__ x,
                                                 const int* __restrict__ idx,
                                                 const float* __restrict__ sumExp,
                                                 const float* __restrict__ tExp,
                                                 const int* __restrict__ targets,
                                                 float* __restrict__ out,
                                                 float* __restrict__ out1) {
  int t = threadIdx.x;
  if (blockIdx.x == 256) {          // ---- loss reduction block ----
    float a = 0.f, bsum = 0.f;
#pragma unroll
    for (int k = 0; k < 4; k++) {
      int b = t + k * 256;
      float S = sumExp[b], tE = tExp[b];
      float nll = -logf(tE / (S + 1e-6f) + 1e-6f);
      float valid = (targets[b] != 750) ? 1.f : 0.f;
      a += nll * valid; bsum += valid;
    }
#pragma unroll
    for (int o = 32; o > 0; o >>= 1) {
      a += __shfl_down(a, o, 64);
      bsum += __shfl_down(bsum, o, 64);
    }
    __shared__ float ra[4], rb[4];
    if ((t & 63) == 0) { ra[t >> 6] = a; rb[t >> 6] = bsum; }
    __syncthreads();
    if (t == 0) {
      float sa = ra[0] + ra[1] + ra[2] + ra[3];
      float sb = rb[0] + rb[1] + rb[2] + rb[3];
      out[0] = sa / fmaxf(sb, 1.f);
    }
    return;
  }
  // ---- momentum update blocks ----
  __shared__ int ilds[Bn];
  for (int i = t; i < Bn; i += 256) ilds[i] = idx[i];
  __syncthreads();
  int wid = t >> 6, lane = t & 63;
  int b = blockIdx.x * 4 + wid;
  int y = ilds[b];
  // am I the first occurrence of y?
  for (int base = 0; base < b; base += 64) {
    int j = base + lane;
    bool hit = (j < b) && (ilds[j] == y);
    if (__any(hit)) return;   // wave-uniform exit (no syncthreads below)
  }
  float4 r = *(const float4*)&features[y * Fdim + lane * 4];
  for (int base = (b >> 6) << 6; base < Bn; base += 64) {
    int k = base + lane;
    bool hit = (k >= b) && (ilds[k] == y);
    unsigned long long mbits = __ballot(hit);
    while (mbits) {
      int p = __ffsll(mbits) - 1;
      mbits &= mbits - 1;
      int kk = base + p;
      float4 xv = *(const float4*)&x[kk * Fdim + lane * 4];
      r.x = MOM * r.x + (1.f - MOM) * xv.x;
      r.y = MOM * r.y + (1.f - MOM) * xv.y;
      r.z = MOM * r.z + (1.f - MOM) * xv.z;
      r.w = MOM * r.w + (1.f - MOM) * xv.w;
      float ss = r.x * r.x + r.y * r.y + r.z * r.z + r.w * r.w;
#pragma unroll
      for (int o = 32; o > 0; o >>= 1) ss += __shfl_xor(ss, o, 64);
      float inv = 1.0f / sqrtf(ss);
      r.x *= inv; r.y *= inv; r.z *= inv; r.w *= inv;
    }
  }
  int base2 = y * Fdim + lane * 4;   // out1 is off-by-1 misaligned -> scalar stores
  out1[base2 + 0] = r.x;
  out1[base2 + 1] = r.y;
  out1[base2 + 2] = r.z;
  out1[base2 + 3] = r.w;
}

extern "C" void kernel_launch(void* const* d_in, const int* in_sizes, int n_in,
                              void* d_out, int out_size, void* d_ws, size_t ws_size,
                              hipStream_t stream) {
  const float* inputs   = (const float*)d_in[0];
  const int*   indexes  = (const int*)d_in[1];
  const float* features = (const float*)d_in[2];
  const int*   labels   = (const int*)d_in[3];
  float* out = (float*)d_out;          // out[0] = loss, out[1..] = new_features
  WS* w = (WS*)d_ws;

  // one memset zeroes meanP + counts + sumExp (contiguous tail of WS)
  hipMemsetAsync(w->meanP, 0, (size_t)(Fdim * Cn + Cn + Bn) * 4, stream);
  k1_norm<<<Bn, 64, 0, stream>>>(inputs, indexes, labels, w->x, w->idx, w->targets,
                                 w->counts);
  k3_scan<<<1, 1024, 0, stream>>>(w->counts, w->offsets, w->cursor);
  k4_fill<<<Nn / 1024, 256, 0, stream>>>(labels, w->cursor, w->list);
  k5_fused<<<Nn / 64, 256, 0, stream>>>(features, w->list, labels, w->meanP, out + 1);
  k6_matmul<<<dim3(Bn / BBT, 4), 256, 0, stream>>>(w->x, w->meanP, w->counts, w->targets,
                                                   w->sumExp, w->tExp);
  k8_update<<<Bn / 4 + 1, 256, 0, stream>>>(features, w->x, w->idx, w->sumExp, w->tExp,
                                            w->targets, out, out + 1);
}

// Round 8
// 213.768 us; speedup vs baseline: 1.2877x; 1.2877x over previous
//
#include <hip/hip_runtime.h>
#include <math.h>

#define Bn   1024
#define Fdim 256
#define Nn   65536
#define Cn   1000
#define INV_TEMP 20.0f
#define MOM  0.2f

// ---------------- workspace layout (all 4-byte types, no padding) ----------
// meanC, counts, sumExp contiguous at the tail -> zeroed by ONE memset.
struct WS {
  float x[Bn * Fdim];       // normalized inputs                    (1 MB)
  float meanP[Fdim * Cn];   // class means, packed [f/4][Cn][4]     (1 MB)
  float tExp[Bn];
  int   idx[Bn];
  int   targets[Bn];
  int   offsets[Cn];
  int   cursor[Cn];
  int   list[Nn];
  // ---- zero region start ----
  float meanC[Cn * Fdim];   // class sums, [c][f] layout            (1 MB)
  int   counts[Cn];
  float sumExp[Bn];
  // ---- zero region end ----
};

// K1: x = inputs/||inputs|| (one wave per row, float4) + idx/target remap
//     + fused label histogram (this grid has exactly Nn threads).
__global__ __launch_bounds__(64) void k1_norm(const float* __restrict__ inputs,
                                              const int* __restrict__ indexes,
                                              const int* __restrict__ labels,
                                              float* __restrict__ x,
                                              int* __restrict__ idx, int* __restrict__ targets,
                                              int* __restrict__ counts) {
  int b = blockIdx.x, t = threadIdx.x;
  atomicAdd(&counts[labels[b * 64 + t]], 1);   // histogram: one thread per bank row
  float4 v = *(const float4*)&inputs[b * Fdim + t * 4];
  float s = v.x * v.x + v.y * v.y + v.z * v.z + v.w * v.w;
#pragma unroll
  for (int o = 32; o > 0; o >>= 1) s += __shfl_xor(s, o, 64);
  float inv = 1.0f / sqrtf(s);
  v.x *= inv; v.y *= inv; v.z *= inv; v.w *= inv;
  *(float4*)&x[b * Fdim + t * 4] = v;
  if (t == 0) {
    int i0 = indexes[b] - 1;
    if (i0 == 5554) i0 = 750;   // is_source special case -> SOURCE_CLASSES-1
    idx[b] = i0;
    targets[b] = labels[i0];
  }
}

// K3: exclusive scan of counts -> offsets, cursor (single block, 1024 threads)
__global__ void k3_scan(const int* __restrict__ counts, int* __restrict__ offsets,
                        int* __restrict__ cursor) {
  __shared__ int s[1024];
  int t = threadIdx.x;
  int v = (t < Cn) ? counts[t] : 0;
  s[t] = v;
  __syncthreads();
  for (int o = 1; o < 1024; o <<= 1) {
    int a = (t >= o) ? s[t - o] : 0;
    __syncthreads();
    s[t] += a;
    __syncthreads();
  }
  if (t < Cn) {
    int off = s[t] - v;
    offsets[t] = off;
    cursor[t] = off;
  }
}

// K4: fill per-class member lists (int4 loads) -> list is class-sorted
__global__ __launch_bounds__(256) void k4_fill(const int* __restrict__ labels,
                                               int* __restrict__ cursor,
                                               int* __restrict__ list) {
  int t = blockIdx.x * blockDim.x + threadIdx.x;
  int4 l = *(const int4*)&labels[t * 4];
  int n = t * 4;
  list[atomicAdd(&cursor[l.x], 1)] = n;
  list[atomicAdd(&cursor[l.y], 1)] = n + 1;
  list[atomicAdd(&cursor[l.z], 1)] = n + 2;
  list[atomicAdd(&cursor[l.w], 1)] = n + 3;
}

// K5: fused bank-copy + class-sum over the class-sorted list. Wave g handles
// entries [g*16, g*16+16). Run-boundary flushes (~1.24/wave expected) go to
// meanC[c][f]: the wave's 64 lanes hit ONE contiguous 1KB region (coalesced
// atomics — the packed-layout scatter variant cost +38MB HBM writeback and
// 2.4x time in round 7).
__global__ __launch_bounds__(256) void k5_fused(const float* __restrict__ features,
                                                const int* __restrict__ list,
                                                const int* __restrict__ labels,
                                                float* __restrict__ meanC,
                                                float* __restrict__ out1) {
  int w = blockIdx.x * 4 + (threadIdx.x >> 6);   // global wave id, 0..4095
  int lane = threadIdx.x & 63;
  int e0 = w * 16;
  int r[16], cc[16];
#pragma unroll
  for (int j = 0; j < 16; j++) r[j] = list[e0 + j];      // wave-uniform
#pragma unroll
  for (int j = 0; j < 16; j++) cc[j] = labels[r[j]];     // wave-uniform
  float4 acc = {0.f, 0.f, 0.f, 0.f};
  int cur = cc[0];
#pragma unroll
  for (int bh = 0; bh < 2; bh++) {
    float4 v[8];
#pragma unroll
    for (int j = 0; j < 8; j++)
      v[j] = *(const float4*)&features[(size_t)r[bh * 8 + j] * Fdim + lane * 4];
#pragma unroll
    for (int j = 0; j < 8; j++) {
      int e = bh * 8 + j;
      float* o = &out1[(size_t)r[e] * Fdim + lane * 4];  // +1 misaligned -> dword stores
      o[0] = v[j].x; o[1] = v[j].y; o[2] = v[j].z; o[3] = v[j].w;
      if (cc[e] != cur) {                                // wave-uniform branch
        float* p = &meanC[(size_t)cur * Fdim + lane * 4];
        atomicAdd(p + 0, acc.x); atomicAdd(p + 1, acc.y);
        atomicAdd(p + 2, acc.z); atomicAdd(p + 3, acc.w);
        acc.x = 0.f; acc.y = 0.f; acc.z = 0.f; acc.w = 0.f;
        cur = cc[e];
      }
      acc.x += v[j].x; acc.y += v[j].y; acc.z += v[j].z; acc.w += v[j].w;
    }
  }
  float* p = &meanC[(size_t)cur * Fdim + lane * 4];
  atomicAdd(p + 0, acc.x); atomicAdd(p + 1, acc.y);
  atomicAdd(p + 2, acc.z); atomicAdd(p + 3, acc.w);
}

// K5t: meanC [c][f] -> packed meanP [f/4][c][4] (raw sums; scaling in k6).
__global__ __launch_bounds__(256) void k5t_pack(const float* __restrict__ meanC,
                                                float* __restrict__ meanP) {
  int c = blockIdx.x, t = threadIdx.x;
  float s = meanC[c * Fdim + t];
  meanP[((t >> 2) * Cn + c) * 4 + (t & 3)] = s;
}

// K6: sim = (x @ classSum^T) * (INV_TEMP/cnt) fused with masked-softmax
// partials. BBT=8 halves meanP L2 re-reads vs BBT=4 (128 MB total). Mask and
// mean-scaling come straight from counts[] (no separate mask pass).
#define BBT 8
__global__ __launch_bounds__(256) void k6_matmul(const float* __restrict__ x,
                                                 const float* __restrict__ meanP,
                                                 const int* __restrict__ counts,
                                                 const int* __restrict__ targets,
                                                 float* __restrict__ sumExp,
                                                 float* __restrict__ tExp) {
  int b0 = blockIdx.x * BBT;
  int c  = blockIdx.y * 256 + threadIdx.x;
  int lane = threadIdx.x & 63;
  bool cv = (c < Cn);
  int cc = cv ? c : 0;
  float acc[BBT];
#pragma unroll
  for (int bb = 0; bb < BBT; bb++) acc[bb] = 0.f;
  const float* xb = x + b0 * Fdim;
#pragma unroll 4
  for (int f4 = 0; f4 < Fdim / 4; f4++) {
    float4 mv = *(const float4*)&meanP[(f4 * Cn + cc) * 4];
#pragma unroll
    for (int bb = 0; bb < BBT; bb++) {
      float4 xv = *(const float4*)&xb[bb * Fdim + f4 * 4];   // uniform address (L1-hot)
      acc[bb] = fmaf(xv.x, mv.x, acc[bb]);
      acc[bb] = fmaf(xv.y, mv.y, acc[bb]);
      acc[bb] = fmaf(xv.z, mv.z, acc[bb]);
      acc[bb] = fmaf(xv.w, mv.w, acc[bb]);
    }
  }
  int cnt = counts[cc];
  bool live = cv && (cnt > 0);
  float scale = live ? (INV_TEMP / (float)cnt) : 0.f;
#pragma unroll
  for (int bb = 0; bb < BBT; bb++) {
    float e = live ? __expf(acc[bb] * scale) : 0.f;
    float s = e;
#pragma unroll
    for (int o = 32; o > 0; o >>= 1) s += __shfl_down(s, o, 64);
    if (lane == 0) atomicAdd(&sumExp[b0 + bb], s);
    int tgt = targets[b0 + bb];
    if (cv && tgt == c) tExp[b0 + bb] = e;
  }
}

// K8: sequential momentum scatter update (blocks 0..255) + final loss
// reduction (block 256). One wave per sample b; only the first occurrence of
// each index runs, processing its whole duplicate chain in ascending b order.
__global__ __launch_bounds__(256) void k8_update(const float* __restrict__ features,
                                                 const float* __restrict__ x,
                                                 const int* __restrict__ idx,
                                                 const float* __restrict__ sumExp,
                                                 const float* __restrict__ tExp,
                                                 const int* __restrict__ targets,
                                                 float* __restrict__ out,
                                                 float* __restrict__ out1) {
  int t = threadIdx.x;
  if (blockIdx.x == 256) {          // ---- loss reduction block ----
    float a = 0.f, bsum = 0.f;
#pragma unroll
    for (int k = 0; k < 4; k++) {
      int b = t + k * 256;
      float S = sumExp[b], tE = tExp[b];
      float nll = -logf(tE / (S + 1e-6f) + 1e-6f);
      float valid = (targets[b] != 750) ? 1.f : 0.f;
      a += nll * valid; bsum += valid;
    }
#pragma unroll
    for (int o = 32; o > 0; o >>= 1) {
      a += __shfl_down(a, o, 64);
      bsum += __shfl_down(bsum, o, 64);
    }
    __shared__ float ra[4], rb[4];
    if ((t & 63) == 0) { ra[t >> 6] = a; rb[t >> 6] = bsum; }
    __syncthreads();
    if (t == 0) {
      float sa = ra[0] + ra[1] + ra[2] + ra[3];
      float sb = rb[0] + rb[1] + rb[2] + rb[3];
      out[0] = sa / fmaxf(sb, 1.f);
    }
    return;
  }
  // ---- momentum update blocks ----
  __shared__ int ilds[Bn];
  for (int i = t; i < Bn; i += 256) ilds[i] = idx[i];
  __syncthreads();
  int wid = t >> 6, lane = t & 63;
  int b = blockIdx.x * 4 + wid;
  int y = ilds[b];
  // am I the first occurrence of y?
  for (int base = 0; base < b; base += 64) {
    int j = base + lane;
    bool hit = (j < b) && (ilds[j] == y);
    if (__any(hit)) return;   // wave-uniform exit (no syncthreads below)
  }
  float4 r = *(const float4*)&features[y * Fdim + lane * 4];
  for (int base = (b >> 6) << 6; base < Bn; base += 64) {
    int k = base + lane;
    bool hit = (k >= b) && (ilds[k] == y);
    unsigned long long mbits = __ballot(hit);
    while (mbits) {
      int p = __ffsll(mbits) - 1;
      mbits &= mbits - 1;
      int kk = base + p;
      float4 xv = *(const float4*)&x[kk * Fdim + lane * 4];
      r.x = MOM * r.x + (1.f - MOM) * xv.x;
      r.y = MOM * r.y + (1.f - MOM) * xv.y;
      r.z = MOM * r.z + (1.f - MOM) * xv.z;
      r.w = MOM * r.w + (1.f - MOM) * xv.w;
      float ss = r.x * r.x + r.y * r.y + r.z * r.z + r.w * r.w;
#pragma unroll
      for (int o = 32; o > 0; o >>= 1) ss += __shfl_xor(ss, o, 64);
      float inv = 1.0f / sqrtf(ss);
      r.x *= inv; r.y *= inv; r.z *= inv; r.w *= inv;
    }
  }
  int base2 = y * Fdim + lane * 4;   // out1 is off-by-1 misaligned -> scalar stores
  out1[base2 + 0] = r.x;
  out1[base2 + 1] = r.y;
  out1[base2 + 2] = r.z;
  out1[base2 + 3] = r.w;
}

extern "C" void kernel_launch(void* const* d_in, const int* in_sizes, int n_in,
                              void* d_out, int out_size, void* d_ws, size_t ws_size,
                              hipStream_t stream) {
  const float* inputs   = (const float*)d_in[0];
  const int*   indexes  = (const int*)d_in[1];
  const float* features = (const float*)d_in[2];
  const int*   labels   = (const int*)d_in[3];
  float* out = (float*)d_out;          // out[0] = loss, out[1..] = new_features
  WS* w = (WS*)d_ws;

  // one memset zeroes meanC + counts + sumExp (contiguous tail of WS)
  hipMemsetAsync(w->meanC, 0, (size_t)(Cn * Fdim + Cn + Bn) * 4, stream);
  k1_norm<<<Bn, 64, 0, stream>>>(inputs, indexes, labels, w->x, w->idx, w->targets,
                                 w->counts);
  k3_scan<<<1, 1024, 0, stream>>>(w->counts, w->offsets, w->cursor);
  k4_fill<<<Nn / 1024, 256, 0, stream>>>(labels, w->cursor, w->list);
  k5_fused<<<Nn / 64, 256, 0, stream>>>(features, w->list, labels, w->meanC, out + 1);
  k5t_pack<<<Cn, 256, 0, stream>>>(w->meanC, w->meanP);
  k6_matmul<<<dim3(Bn / BBT, 4), 256, 0, stream>>>(w->x, w->meanP, w->counts, w->targets,
                                                   w->sumExp, w->tExp);
  k8_update<<<Bn / 4 + 1, 256, 0, stream>>>(features, w->x, w->idx, w->sumExp, w->tExp,
                                            w->targets, out, out + 1);
}